// Round 1
// baseline (890.829 us; speedup 1.0000x reference)
//
#include <hip/hip_runtime.h>

namespace {

constexpr int B_ = 128;
constexpr int T_ = 4096;
constexpr int BT = B_ * T_;
constexpr int TTILE = 128;
constexpr unsigned INFBITS = 0x7F800000u;

// workspace layout (float offsets); total 32 MB
constexpr size_t OFF_FEATS = 0;
constexpr size_t OFF_HC   = (size_t)B_ * 10 * T_;          // 5,242,880
constexpr size_t OFF_AN   = OFF_HC + (size_t)BT;
constexpr size_t OFF_SC   = OFF_AN + (size_t)BT;
constexpr size_t OFF_OT   = OFF_SC + (size_t)BT;
constexpr size_t OFF_RULE = OFF_OT + (size_t)BT;
constexpr size_t OFF_LP   = OFF_RULE + (size_t)BT;

__device__ __forceinline__ float gelu_exact(float x) {
  return 0.5f * x * (1.0f + erff(x * 0.7071067811865475f));
}
__device__ __forceinline__ float clip01(float x) { return fminf(fmaxf(x, 0.f), 1.f); }

// ---------------- Kernel A: featurize ----------------
__global__ __launch_bounds__(256)
void featurize_k(const float* __restrict__ traj, const float* __restrict__ intervals,
                 const float* __restrict__ amask, const float* __restrict__ omask,
                 float* __restrict__ feats, float* __restrict__ hc, float* __restrict__ an,
                 float* __restrict__ sc, float* __restrict__ ot) {
  int idx = blockIdx.x * 256 + threadIdx.x;
  if (idx >= BT) return;
  int b = idx >> 12;
  int t = idx & (T_ - 1);
  const float* tr = traj + (size_t)b * T_ * 2;
  const float* iv = intervals + (size_t)b * T_;
  const float* mk = amask + (size_t)b * T_;
  const float* om = omask + (size_t)b * T_;
  float m  = mk[t];
  float m1 = (t >= 1) ? mk[t - 1] : 0.f;
  float m2 = (t >= 2) ? mk[t - 2] : 0.f;
  float pm01 = (m > 0.5f && m1 > 0.5f) ? 1.f : 0.f;   // pm[t-1]
  float pm12 = (m1 > 0.5f && m2 > 0.5f) ? 1.f : 0.f;  // pm[t-2]
  float x0x = tr[2 * t] * m, x0y = tr[2 * t + 1] * m;
  float x1x = 0.f, x1y = 0.f, x2x = 0.f, x2y = 0.f;
  if (t >= 1) { x1x = tr[2 * (t - 1)] * m1; x1y = tr[2 * (t - 1) + 1] * m1; }
  if (t >= 2) { x2x = tr[2 * (t - 2)] * m2; x2y = tr[2 * (t - 2) + 1] * m2; }
  float dt0 = fmaxf(iv[t], 1e-3f);
  float dt1 = (t >= 1) ? fmaxf(iv[t - 1], 1e-3f) : 1e-3f;
  float vx = 0.f, vy = 0.f, v1x = 0.f, v1y = 0.f;
  if (t >= 1) { vx = (x0x - x1x) * pm01 / dt0 * m; vy = (x0y - x1y) * pm01 / dt0 * m; }
  if (t >= 2) { v1x = (x1x - x2x) * pm12 / dt1 * m1; v1y = (x1y - x2y) * pm12 / dt1 * m1; }
  float ax = 0.f, ay = 0.f;
  if (t >= 1) { ax = (vx - v1x) * pm01 / dt0 * m; ay = (vy - v1y) * pm01 / dt0 * m; }
  float s2 = vx * vx + vy * vy;
  float speed = (s2 > 0.f ? sqrtf(s2) : 0.f) * m;
  float s21 = v1x * v1x + v1y * v1y;
  float speed1 = (s21 > 0.f ? sqrtf(s21) : 0.f) * m1;
  float scv = (t >= 1) ? fabsf((speed - speed1) * pm01) * m : 0.f;
  float a2 = ax * ax + ay * ay;
  float anv = (a2 > 0.f ? sqrtf(a2) : 0.f) * m;
  float hcv = 0.f;
  if (t >= 1) {
    float h0 = atan2f(vy, vx), h1 = atan2f(v1y, v1x);
    float d = h0 - h1;
    hcv = fabsf(atan2f(sinf(d), cosf(d))) * pm01 * m;
  }
  float obs = om[t] * m;
  float otv = (t >= 1) ? fminf(fabsf(om[t] - om[t - 1]) * pm01 * m, 1.f) : 0.f;
  float itf = iv[t] * m;
  size_t fb = (size_t)b * 10 * T_ + t;
  feats[fb + 0 * T_] = x0x; feats[fb + 1 * T_] = x0y;
  feats[fb + 2 * T_] = vx;  feats[fb + 3 * T_] = vy;
  feats[fb + 4 * T_] = ax;  feats[fb + 5 * T_] = ay;
  feats[fb + 6 * T_] = speed; feats[fb + 7 * T_] = hcv;
  feats[fb + 8 * T_] = itf;   feats[fb + 9 * T_] = obs;
  hc[idx] = hcv; an[idx] = anv; sc[idx] = scv; ot[idx] = otv;
}

// ---------------- Kernel B: rule scores (exact percentile selects) ----------------
__device__ __forceinline__ void find_bucket(unsigned* hist, unsigned* psum, int nb,
                                            unsigned* selb, unsigned* selk, int tid) {
  int chunk = nb >> 8;  // 16 (nb=4096) or 1 (nb=256)
  unsigned ps = 0;
  for (int c = 0; c < chunk; ++c) ps += hist[tid * chunk + c];
  psum[tid] = ps;
  __syncthreads();
  if (tid == 0) {
    unsigned kk = *selk, run = 0;
    int seg = 0;
    for (; seg < 255; ++seg) { unsigned c = psum[seg]; if (run + c > kk) break; run += c; }
    int bin = seg * chunk, bend = bin + chunk - 1;
    for (; bin < bend; ++bin) { unsigned c = hist[bin]; if (run + c > kk) break; run += c; }
    *selb = (unsigned)bin;
    *selk = kk - run;
  }
  __syncthreads();
}

// exact k-th smallest (by float bits; all candidates >= +0, invalid = +inf)
__device__ __forceinline__ float radix_select(const unsigned* u, unsigned k, unsigned* hist,
                                              unsigned* psum, unsigned* selb, unsigned* selk,
                                              int tid) {
  for (int i = tid; i < 4096; i += 256) hist[i] = 0u;
  if (tid == 0) *selk = k;
  __syncthreads();
#pragma unroll
  for (int r = 0; r < 16; ++r) atomicAdd(&hist[u[r] >> 20], 1u);
  __syncthreads();
  find_bucket(hist, psum, 4096, selb, selk, tid);
  unsigned p1 = *selb;
  for (int i = tid; i < 4096; i += 256) hist[i] = 0u;
  __syncthreads();
#pragma unroll
  for (int r = 0; r < 16; ++r)
    if ((u[r] >> 20) == p1) atomicAdd(&hist[(u[r] >> 8) & 0xFFFu], 1u);
  __syncthreads();
  find_bucket(hist, psum, 4096, selb, selk, tid);
  unsigned p2 = *selb;
  unsigned pref = (p1 << 12) | p2;
  for (int i = tid; i < 256; i += 256) hist[i] = 0u;
  __syncthreads();
#pragma unroll
  for (int r = 0; r < 16; ++r)
    if ((u[r] >> 8) == pref) atomicAdd(&hist[u[r] & 0xFFu], 1u);
  __syncthreads();
  find_bucket(hist, psum, 256, selb, selk, tid);
  unsigned p3 = *selb;
  __syncthreads();
  return __uint_as_float((p1 << 20) | (p2 << 8) | p3);
}

__device__ __forceinline__ float block_max(float v, float* s4, int tid) {
#pragma unroll
  for (int off = 32; off; off >>= 1) v = fmaxf(v, __shfl_xor(v, off));
  if ((tid & 63) == 0) s4[tid >> 6] = v;
  __syncthreads();
  v = fmaxf(fmaxf(s4[0], s4[1]), fmaxf(s4[2], s4[3]));
  __syncthreads();
  return v;
}

__global__ __launch_bounds__(256)
void rule_k(const float* __restrict__ hc, const float* __restrict__ an,
            const float* __restrict__ sc, const float* __restrict__ ot,
            const float* __restrict__ amask, float* __restrict__ rule) {
  __shared__ unsigned hist[4096];
  __shared__ unsigned psum[256];
  __shared__ float vbuf[4096];
  __shared__ unsigned selb, selk;
  __shared__ float s4[4];
  __shared__ int i4[4];
  __shared__ int n_sh;
  __shared__ float scale_sh[4];
  int b = blockIdx.x, tid = threadIdx.x;
  const float* mrow = amask + (size_t)b * T_;
  float mreg[16];
  int cnt = 0;
#pragma unroll
  for (int r = 0; r < 16; ++r) { mreg[r] = mrow[tid + 256 * r]; cnt += (mreg[r] > 0.5f); }
#pragma unroll
  for (int off = 32; off; off >>= 1) cnt += __shfl_xor(cnt, off);
  if ((tid & 63) == 0) i4[tid >> 6] = cnt;
  __syncthreads();
  if (tid == 0) n_sh = i4[0] + i4[1] + i4[2] + i4[3];
  __syncthreads();
  int n = n_sh;
  int cidx = (int)ceilf((float)n * 0.95f);
  if (cidx < 1) cidx = 1;
  int kidx = cidx - 1;
  if (kidx < 0) kidx = 0;
  if (kidx > T_ - 1) kidx = T_ - 1;

  const float* rows[3] = { hc + (size_t)b * T_, an + (size_t)b * T_, sc + (size_t)b * T_ };
  for (int a3 = 0; a3 < 3; ++a3) {
    const float* arr = rows[a3];
    unsigned u[16];
    float mx = 0.f;
#pragma unroll
    for (int r = 0; r < 16; ++r) {
      float v = arr[tid + 256 * r];
      if (mreg[r] > 0.5f) {
        mx = fmaxf(mx, fabsf(v));
        unsigned ub = __float_as_uint(v);
        if ((int)ub < 0) ub = 0u;  // -0.0 safety
        u[r] = ub;
      } else u[r] = INFBITS;
    }
    mx = block_max(mx, s4, tid);
    float kth = fabsf(radix_select(u, (unsigned)kidx, hist, psum, &selb, &selk, tid));
    if (tid == 0) {
      float s = (kth < 1e-6f) ? mx : kth;
      scale_sh[a3] = fmaxf(s, 1e-6f);
    }
  }
  __syncthreads();
  float sc0 = scale_sh[0], sc1 = scale_sh[1], sc2 = scale_sh[2];
  const float* otrow = ot + (size_t)b * T_;
#pragma unroll
  for (int r = 0; r < 16; ++r) {
    int t = tid + 256 * r;
    float v = 0.f;
    if (n > 0) {
      v = 0.35f * (rows[0][t] / sc0) + 0.30f * (rows[1][t] / sc1)
        + 0.25f * (rows[2][t] / sc2) + 0.10f * otrow[t];
    }
    vbuf[t] = v;
  }
  __syncthreads();
  float sm[16];
#pragma unroll
  for (int r = 0; r < 16; ++r) {
    int t = tid + 256 * r;
    float s = 0.f;
#pragma unroll
    for (int d = -2; d <= 2; ++d) {
      int tt = t + d;
      if (tt >= 0 && tt < T_) s += vbuf[tt];
    }
    sm[r] = s * 0.2f * mreg[r];
  }
  unsigned u2[16];
  float mx2 = 0.f;
#pragma unroll
  for (int r = 0; r < 16; ++r) {
    if (mreg[r] > 0.5f) {
      mx2 = fmaxf(mx2, fabsf(sm[r]));
      unsigned ub = __float_as_uint(sm[r]);
      if ((int)ub < 0) ub = 0u;
      u2[r] = ub;
    } else u2[r] = INFBITS;
  }
  mx2 = block_max(mx2, s4, tid);
  float kth4 = fabsf(radix_select(u2, (unsigned)kidx, hist, psum, &selb, &selk, tid));
  float scale4 = fmaxf((kth4 < 1e-6f) ? mx2 : kth4, 1e-6f);
  float* rrow = rule + (size_t)b * T_;
#pragma unroll
  for (int r = 0; r < 16; ++r) {
    int t = tid + 256 * r;
    float v = (n > 0) ? sm[r] / scale4 : 0.f;
    rrow[t] = clip01(v) * mreg[r];
  }
}

// ---------------- Kernel C: fused conv1+GELU -> conv2+GELU -> conv3+sigmoid ----------------
__global__ __launch_bounds__(512)
void conv_k(const float* __restrict__ feats, const float* __restrict__ w1g,
            const float* __restrict__ b1g, const float* __restrict__ w2g,
            const float* __restrict__ b2g, const float* __restrict__ w3g,
            const float* __restrict__ b3g, const float* __restrict__ amask,
            float* __restrict__ lp) {
  // sH[o][j], j in [0,136): j <-> global t = t0-4+j; h1 valid for j in [2,134)
  __shared__ __align__(16) float sH[64 * 136];
  // union region: phase1 = sF[10*136] + sW1[3200]; phase2 chunks = sW2c[2560]
  __shared__ __align__(16) float sR[4560];
  int tid = threadIdx.x;
  int tile = blockIdx.x, b = blockIdx.y;
  int t0 = tile * TTILE;
  const float* frow = feats + (size_t)b * 10 * T_;
  for (int s = tid; s < 1360; s += 512) {
    int c = s / 136, j = s - c * 136;
    int t = t0 - 4 + j;
    sR[s] = (t >= 0 && t < T_) ? frow[(size_t)c * T_ + t] : 0.f;
  }
  for (int s = tid; s < 3200; s += 512) sR[1360 + s] = w1g[s];
  if (tid < 64) {
    sH[tid * 136 + 0] = 0.f; sH[tid * 136 + 1] = 0.f;
    sH[tid * 136 + 134] = 0.f; sH[tid * 136 + 135] = 0.f;
  }
  __syncthreads();
  // phase 1: conv1 + GELU into sH; thread = (o, jg), lanes vary mostly in jg -> conflict-free stores
  {
    int o = tid >> 3, jg = tid & 7;
    int j0 = 2 + jg * 17;
    float wr[50];
#pragma unroll
    for (int c = 0; c < 50; ++c) wr[c] = sR[1360 + o * 50 + c];
    float bias = b1g[o];
    float acc[17];
#pragma unroll
    for (int jj = 0; jj < 17; ++jj) acc[jj] = bias;
#pragma unroll
    for (int i = 0; i < 10; ++i) {
      float win[21];
#pragma unroll
      for (int c = 0; c < 21; ++c) {
        int jf = j0 - 2 + c;
        win[c] = sR[i * 136 + (jf < 136 ? jf : 135)];  // clamp: overflow lanes discarded below
      }
#pragma unroll
      for (int k = 0; k < 5; ++k)
#pragma unroll
        for (int jj = 0; jj < 17; ++jj)
          acc[jj] += wr[i * 5 + k] * win[jj + k];
    }
#pragma unroll
    for (int jj = 0; jj < 17; ++jj) {
      int j = j0 + jj;
      if (j < 134) {
        int t = t0 - 4 + j;
        sH[o * 136 + j] = (t >= 0 && t < T_) ? gelu_exact(acc[jj]) : 0.f;  // conv2 zero-pad
      }
    }
  }
  // phase 2: conv2; wave = one g, lanes = 64 output channels -> h1 window reads broadcast
  int o = tid & 63, g = tid >> 6;
  float acc2[16];
  float bias2 = b2g[o];
#pragma unroll
  for (int tt = 0; tt < 16; ++tt) acc2[tt] = bias2;
  for (int ic = 0; ic < 64; ic += 8) {
    __syncthreads();
    for (int s = tid; s < 2560; s += 512) {
      int oo = s / 40, c = s - oo * 40;
      sR[s] = w2g[(size_t)oo * 320 + ic * 5 + c];  // [o][8ch*5k] chunk
    }
    __syncthreads();
#pragma unroll
    for (int ip = 0; ip < 8; ++ip) {
      const float* hrow = &sH[(ic + ip) * 136 + g * 16];
      float win[24];
#pragma unroll
      for (int q = 0; q < 6; ++q) {
        float4 v = *reinterpret_cast<const float4*>(hrow + q * 4);
        win[q * 4 + 0] = v.x; win[q * 4 + 1] = v.y;
        win[q * 4 + 2] = v.z; win[q * 4 + 3] = v.w;
      }
      float w5[5];
#pragma unroll
      for (int k = 0; k < 5; ++k) w5[k] = sR[o * 40 + ip * 5 + k];
#pragma unroll
      for (int k = 0; k < 5; ++k)
#pragma unroll
        for (int tt = 0; tt < 16; ++tt)
          acc2[tt] += w5[k] * win[tt + k + 2];
    }
  }
  // epilogue: gelu, conv3 (dot over lanes = channels), sigmoid
  float w3v = w3g[o];
  float b3v = b3g[0];
  float keep = 0.f;
#pragma unroll
  for (int tt = 0; tt < 16; ++tt) {
    float s = w3v * gelu_exact(acc2[tt]);
#pragma unroll
    for (int off = 32; off; off >>= 1) s += __shfl_xor(s, off);
    if (o == tt) keep = s;
  }
  if (o < 16) {
    int t = t0 + g * 16 + o;
    float m = amask[(size_t)b * T_ + t];
    float val = 1.f / (1.f + expf(-(keep + b3v)));
    lp[(size_t)b * T_ + t] = val * m;
  }
}

// ---------------- Kernel D: smooth learned + blend ----------------
__global__ __launch_bounds__(256)
void final_k(const float* __restrict__ rule, const float* __restrict__ lp,
             const float* __restrict__ amask, float* __restrict__ out) {
  int idx = blockIdx.x * 256 + threadIdx.x;
  if (idx >= BT) return;
  int t = idx & (T_ - 1);
  float s = 0.f;
#pragma unroll
  for (int d = -2; d <= 2; ++d) {
    int tt = t + d;
    if (tt >= 0 && tt < T_) s += lp[idx + d];
  }
  float m = amask[idx];
  float learned = clip01(s * 0.2f * m);
  out[idx] = clip01(0.5f * rule[idx] + 0.5f * learned) * m;
}

}  // namespace

extern "C" void kernel_launch(void* const* d_in, const int* in_sizes, int n_in,
                              void* d_out, int out_size, void* d_ws, size_t ws_size,
                              hipStream_t stream) {
  const float* traj      = (const float*)d_in[0];
  const float* intervals = (const float*)d_in[1];
  const float* amask     = (const float*)d_in[2];
  const float* omask     = (const float*)d_in[3];
  const float* w1        = (const float*)d_in[4];
  const float* b1        = (const float*)d_in[5];
  const float* w2        = (const float*)d_in[6];
  const float* b2        = (const float*)d_in[7];
  const float* w3        = (const float*)d_in[8];
  const float* b3        = (const float*)d_in[9];
  float* out = (float*)d_out;
  float* ws = (float*)d_ws;

  float* feats = ws + OFF_FEATS;
  float* hc   = ws + OFF_HC;
  float* an   = ws + OFF_AN;
  float* sc   = ws + OFF_SC;
  float* ot   = ws + OFF_OT;
  float* rule = ws + OFF_RULE;
  float* lp   = ws + OFF_LP;

  featurize_k<<<BT / 256, 256, 0, stream>>>(traj, intervals, amask, omask,
                                            feats, hc, an, sc, ot);
  rule_k<<<B_, 256, 0, stream>>>(hc, an, sc, ot, amask, rule);
  conv_k<<<dim3(T_ / TTILE, B_), 512, 0, stream>>>(feats, w1, b1, w2, b2, w3, b3, amask, lp);
  final_k<<<BT / 256, 256, 0, stream>>>(rule, lp, amask, out);
}

// Round 2
// 308.551 us; speedup vs baseline: 2.8871x; 2.8871x over previous
//
#include <hip/hip_runtime.h>

namespace {

constexpr int B_ = 128;
constexpr int T_ = 4096;
constexpr int BT = B_ * T_;
constexpr int TTILE = 128;
constexpr unsigned INFBITS = 0x7F800000u;

// workspace layout (float offsets); footprint identical to round 1 (32 MB)
constexpr size_t OFF_FEATS = 0;
constexpr size_t OFF_HC   = (size_t)B_ * 10 * T_;          // 5,242,880
constexpr size_t OFF_AN   = OFF_HC + (size_t)BT;
constexpr size_t OFF_SC   = OFF_AN + (size_t)BT;
constexpr size_t OFF_OT   = OFF_SC + (size_t)BT;
constexpr size_t OFF_RULE = OFF_OT + (size_t)BT;
constexpr size_t OFF_LP   = OFF_RULE + (size_t)BT;
// weight fragments live in the hc region (dead after rule_k, stream-ordered)
constexpr size_t OFF_W1F  = OFF_HC;               // 8 frags * 64 lanes * 8 f16 = 2048 floats
constexpr size_t OFF_W2F  = OFF_HC + 2048;        // 40 frags * 64 * 8 f16 = 10240 floats

typedef _Float16 half8 __attribute__((ext_vector_type(8)));
typedef _Float16 half4 __attribute__((ext_vector_type(4)));
typedef float f32x4 __attribute__((ext_vector_type(4)));

__device__ __forceinline__ float gelu_exact(float x) {
  return 0.5f * x * (1.0f + erff(x * 0.7071067811865475f));
}
__device__ __forceinline__ float clip01(float x) { return fminf(fmaxf(x, 0.f), 1.f); }

// ---------------- Kernel A: featurize (unchanged) ----------------
__global__ __launch_bounds__(256)
void featurize_k(const float* __restrict__ traj, const float* __restrict__ intervals,
                 const float* __restrict__ amask, const float* __restrict__ omask,
                 float* __restrict__ feats, float* __restrict__ hc, float* __restrict__ an,
                 float* __restrict__ sc, float* __restrict__ ot) {
  int idx = blockIdx.x * 256 + threadIdx.x;
  if (idx >= BT) return;
  int b = idx >> 12;
  int t = idx & (T_ - 1);
  const float* tr = traj + (size_t)b * T_ * 2;
  const float* iv = intervals + (size_t)b * T_;
  const float* mk = amask + (size_t)b * T_;
  const float* om = omask + (size_t)b * T_;
  float m  = mk[t];
  float m1 = (t >= 1) ? mk[t - 1] : 0.f;
  float m2 = (t >= 2) ? mk[t - 2] : 0.f;
  float pm01 = (m > 0.5f && m1 > 0.5f) ? 1.f : 0.f;
  float pm12 = (m1 > 0.5f && m2 > 0.5f) ? 1.f : 0.f;
  float x0x = tr[2 * t] * m, x0y = tr[2 * t + 1] * m;
  float x1x = 0.f, x1y = 0.f, x2x = 0.f, x2y = 0.f;
  if (t >= 1) { x1x = tr[2 * (t - 1)] * m1; x1y = tr[2 * (t - 1) + 1] * m1; }
  if (t >= 2) { x2x = tr[2 * (t - 2)] * m2; x2y = tr[2 * (t - 2) + 1] * m2; }
  float dt0 = fmaxf(iv[t], 1e-3f);
  float dt1 = (t >= 1) ? fmaxf(iv[t - 1], 1e-3f) : 1e-3f;
  float vx = 0.f, vy = 0.f, v1x = 0.f, v1y = 0.f;
  if (t >= 1) { vx = (x0x - x1x) * pm01 / dt0 * m; vy = (x0y - x1y) * pm01 / dt0 * m; }
  if (t >= 2) { v1x = (x1x - x2x) * pm12 / dt1 * m1; v1y = (x1y - x2y) * pm12 / dt1 * m1; }
  float ax = 0.f, ay = 0.f;
  if (t >= 1) { ax = (vx - v1x) * pm01 / dt0 * m; ay = (vy - v1y) * pm01 / dt0 * m; }
  float s2 = vx * vx + vy * vy;
  float speed = (s2 > 0.f ? sqrtf(s2) : 0.f) * m;
  float s21 = v1x * v1x + v1y * v1y;
  float speed1 = (s21 > 0.f ? sqrtf(s21) : 0.f) * m1;
  float scv = (t >= 1) ? fabsf((speed - speed1) * pm01) * m : 0.f;
  float a2 = ax * ax + ay * ay;
  float anv = (a2 > 0.f ? sqrtf(a2) : 0.f) * m;
  float hcv = 0.f;
  if (t >= 1) {
    float h0 = atan2f(vy, vx), h1 = atan2f(v1y, v1x);
    float d = h0 - h1;
    hcv = fabsf(atan2f(sinf(d), cosf(d))) * pm01 * m;
  }
  float obs = om[t] * m;
  float otv = (t >= 1) ? fminf(fabsf(om[t] - om[t - 1]) * pm01 * m, 1.f) : 0.f;
  float itf = iv[t] * m;
  size_t fb = (size_t)b * 10 * T_ + t;
  feats[fb + 0 * T_] = x0x; feats[fb + 1 * T_] = x0y;
  feats[fb + 2 * T_] = vx;  feats[fb + 3 * T_] = vy;
  feats[fb + 4 * T_] = ax;  feats[fb + 5 * T_] = ay;
  feats[fb + 6 * T_] = speed; feats[fb + 7 * T_] = hcv;
  feats[fb + 8 * T_] = itf;   feats[fb + 9 * T_] = obs;
  hc[idx] = hcv; an[idx] = anv; sc[idx] = scv; ot[idx] = otv;
}

// ---------------- Kernel B: rule scores (unchanged) ----------------
__device__ __forceinline__ void find_bucket(unsigned* hist, unsigned* psum, int nb,
                                            unsigned* selb, unsigned* selk, int tid) {
  int chunk = nb >> 8;
  unsigned ps = 0;
  for (int c = 0; c < chunk; ++c) ps += hist[tid * chunk + c];
  psum[tid] = ps;
  __syncthreads();
  if (tid == 0) {
    unsigned kk = *selk, run = 0;
    int seg = 0;
    for (; seg < 255; ++seg) { unsigned c = psum[seg]; if (run + c > kk) break; run += c; }
    int bin = seg * chunk, bend = bin + chunk - 1;
    for (; bin < bend; ++bin) { unsigned c = hist[bin]; if (run + c > kk) break; run += c; }
    *selb = (unsigned)bin;
    *selk = kk - run;
  }
  __syncthreads();
}

__device__ __forceinline__ float radix_select(const unsigned* u, unsigned k, unsigned* hist,
                                              unsigned* psum, unsigned* selb, unsigned* selk,
                                              int tid) {
  for (int i = tid; i < 4096; i += 256) hist[i] = 0u;
  if (tid == 0) *selk = k;
  __syncthreads();
#pragma unroll
  for (int r = 0; r < 16; ++r) atomicAdd(&hist[u[r] >> 20], 1u);
  __syncthreads();
  find_bucket(hist, psum, 4096, selb, selk, tid);
  unsigned p1 = *selb;
  for (int i = tid; i < 4096; i += 256) hist[i] = 0u;
  __syncthreads();
#pragma unroll
  for (int r = 0; r < 16; ++r)
    if ((u[r] >> 20) == p1) atomicAdd(&hist[(u[r] >> 8) & 0xFFFu], 1u);
  __syncthreads();
  find_bucket(hist, psum, 4096, selb, selk, tid);
  unsigned p2 = *selb;
  unsigned pref = (p1 << 12) | p2;
  for (int i = tid; i < 256; i += 256) hist[i] = 0u;
  __syncthreads();
#pragma unroll
  for (int r = 0; r < 16; ++r)
    if ((u[r] >> 8) == pref) atomicAdd(&hist[u[r] & 0xFFu], 1u);
  __syncthreads();
  find_bucket(hist, psum, 256, selb, selk, tid);
  unsigned p3 = *selb;
  __syncthreads();
  return __uint_as_float((p1 << 20) | (p2 << 8) | p3);
}

__device__ __forceinline__ float block_max(float v, float* s4, int tid) {
#pragma unroll
  for (int off = 32; off; off >>= 1) v = fmaxf(v, __shfl_xor(v, off));
  if ((tid & 63) == 0) s4[tid >> 6] = v;
  __syncthreads();
  v = fmaxf(fmaxf(s4[0], s4[1]), fmaxf(s4[2], s4[3]));
  __syncthreads();
  return v;
}

__global__ __launch_bounds__(256)
void rule_k(const float* __restrict__ hc, const float* __restrict__ an,
            const float* __restrict__ sc, const float* __restrict__ ot,
            const float* __restrict__ amask, float* __restrict__ rule) {
  __shared__ unsigned hist[4096];
  __shared__ unsigned psum[256];
  __shared__ float vbuf[4096];
  __shared__ unsigned selb, selk;
  __shared__ float s4[4];
  __shared__ int i4[4];
  __shared__ int n_sh;
  __shared__ float scale_sh[4];
  int b = blockIdx.x, tid = threadIdx.x;
  const float* mrow = amask + (size_t)b * T_;
  float mreg[16];
  int cnt = 0;
#pragma unroll
  for (int r = 0; r < 16; ++r) { mreg[r] = mrow[tid + 256 * r]; cnt += (mreg[r] > 0.5f); }
#pragma unroll
  for (int off = 32; off; off >>= 1) cnt += __shfl_xor(cnt, off);
  if ((tid & 63) == 0) i4[tid >> 6] = cnt;
  __syncthreads();
  if (tid == 0) n_sh = i4[0] + i4[1] + i4[2] + i4[3];
  __syncthreads();
  int n = n_sh;
  int cidx = (int)ceilf((float)n * 0.95f);
  if (cidx < 1) cidx = 1;
  int kidx = cidx - 1;
  if (kidx < 0) kidx = 0;
  if (kidx > T_ - 1) kidx = T_ - 1;

  const float* rows[3] = { hc + (size_t)b * T_, an + (size_t)b * T_, sc + (size_t)b * T_ };
  for (int a3 = 0; a3 < 3; ++a3) {
    const float* arr = rows[a3];
    unsigned u[16];
    float mx = 0.f;
#pragma unroll
    for (int r = 0; r < 16; ++r) {
      float v = arr[tid + 256 * r];
      if (mreg[r] > 0.5f) {
        mx = fmaxf(mx, fabsf(v));
        unsigned ub = __float_as_uint(v);
        if ((int)ub < 0) ub = 0u;
        u[r] = ub;
      } else u[r] = INFBITS;
    }
    mx = block_max(mx, s4, tid);
    float kth = fabsf(radix_select(u, (unsigned)kidx, hist, psum, &selb, &selk, tid));
    if (tid == 0) {
      float s = (kth < 1e-6f) ? mx : kth;
      scale_sh[a3] = fmaxf(s, 1e-6f);
    }
  }
  __syncthreads();
  float sc0 = scale_sh[0], sc1 = scale_sh[1], sc2 = scale_sh[2];
  const float* otrow = ot + (size_t)b * T_;
#pragma unroll
  for (int r = 0; r < 16; ++r) {
    int t = tid + 256 * r;
    float v = 0.f;
    if (n > 0) {
      v = 0.35f * (rows[0][t] / sc0) + 0.30f * (rows[1][t] / sc1)
        + 0.25f * (rows[2][t] / sc2) + 0.10f * otrow[t];
    }
    vbuf[t] = v;
  }
  __syncthreads();
  float sm[16];
#pragma unroll
  for (int r = 0; r < 16; ++r) {
    int t = tid + 256 * r;
    float s = 0.f;
#pragma unroll
    for (int d = -2; d <= 2; ++d) {
      int tt = t + d;
      if (tt >= 0 && tt < T_) s += vbuf[tt];
    }
    sm[r] = s * 0.2f * mreg[r];
  }
  unsigned u2[16];
  float mx2 = 0.f;
#pragma unroll
  for (int r = 0; r < 16; ++r) {
    if (mreg[r] > 0.5f) {
      mx2 = fmaxf(mx2, fabsf(sm[r]));
      unsigned ub = __float_as_uint(sm[r]);
      if ((int)ub < 0) ub = 0u;
      u2[r] = ub;
    } else u2[r] = INFBITS;
  }
  mx2 = block_max(mx2, s4, tid);
  float kth4 = fabsf(radix_select(u2, (unsigned)kidx, hist, psum, &selb, &selk, tid));
  float scale4 = fmaxf((kth4 < 1e-6f) ? mx2 : kth4, 1e-6f);
  float* rrow = rule + (size_t)b * T_;
#pragma unroll
  for (int r = 0; r < 16; ++r) {
    int t = tid + 256 * r;
    float v = (n > 0) ? sm[r] / scale4 : 0.f;
    rrow[t] = clip01(v) * mreg[r];
  }
}

// ---------------- weight repack: build MFMA A-fragments ----------------
// A-frag layout (16x16x32 f16): lane holds A[m = lane&15][k = (lane>>4)*8 + j], j=0..7.
// conv1 K-index ck = k*10 + c (k = tap, c = input chan), pad [50,64) = 0.
// conv2: 5 shifted GEMMs; frag id f2 = (k*2+kk)*4 + m, K-index ic = kk*32 + q*8 + j.
__global__ __launch_bounds__(256)
void repack_k(const float* __restrict__ w1g, const float* __restrict__ w2g,
              half8* __restrict__ w1f, half8* __restrict__ w2f) {
  int gid = blockIdx.x * 256 + threadIdx.x;  // 3072 = 48 frags * 64 lanes
  if (gid >= 48 * 64) return;
  int fid = gid >> 6, lane = gid & 63;
  int qd = lane >> 4, ln = lane & 15;
  half8 v;
  if (fid < 8) {
    int m = fid >> 1, kk = fid & 1;
    int o = m * 16 + ln;
#pragma unroll
    for (int j = 0; j < 8; ++j) {
      int ck = kk * 32 + qd * 8 + j;
      float val = 0.f;
      if (ck < 50) { int k_ = ck / 10, c = ck - 10 * k_; val = w1g[o * 50 + c * 5 + k_]; }
      v[j] = (_Float16)val;
    }
    w1f[fid * 64 + lane] = v;
  } else {
    int f2 = fid - 8;
    int k = f2 >> 3, kk = (f2 >> 2) & 1, m = f2 & 3;
    int o = m * 16 + ln;
#pragma unroll
    for (int j = 0; j < 8; ++j) {
      int ic = kk * 32 + qd * 8 + j;
      v[j] = (_Float16)w2g[o * 320 + ic * 5 + k];
    }
    w2f[f2 * 64 + lane] = v;
  }
}

// ---------------- Kernel C: MFMA conv1+GELU -> conv2+GELU -> conv3+sigmoid ----------------
// f16 inputs with power-of-2 pre-scaling (feats*2^-6, h1*2^-4) to dodge f16 overflow;
// undone exactly in fp32 at acc-init / epilogue. fp32 MFMA accumulation.
__global__ __launch_bounds__(512, 4)
void conv_k(const float* __restrict__ feats, const half8* __restrict__ w1f,
            const float* __restrict__ b1g, const half8* __restrict__ w2f,
            const float* __restrict__ b2g, const float* __restrict__ w3g,
            const float* __restrict__ b3g, const float* __restrict__ amask,
            float* __restrict__ lp) {
  // stride 72 f16 = 144 B: 16B-aligned rows, 36 dwords -> bank-uniform b128 access
  __shared__ _Float16 sIm[144 * 72];   // im2col feats, rows jt=t-(t0-4)... cols ck
  __shared__ _Float16 sH1[132 * 72];   // h1^T [jh = t-(t0-2)][o], *2^-4
  __shared__ float sF[10 * 136];       // fp32 feats tile
  __shared__ float sPart[2][128];      // conv3 partials per m-pair
  int tid = threadIdx.x;
  int lane = tid & 63, w = tid >> 6;
  int qd = lane >> 4, ln = lane & 15;
  int tile = blockIdx.x, b = blockIdx.y;
  int t0 = tile * TTILE;
  const float* frow = feats + (size_t)b * 10 * T_;

  // stage fp32 feats tile (t0-4 .. t0+131)
  for (int s = tid; s < 1360; s += 512) {
    int c = s / 136, u = s - c * 136;
    int t = t0 - 4 + u;
    sF[s] = (t >= 0 && t < T_) ? frow[(size_t)c * T_ + t] : 0.f;
  }
  // zero K-pad cols [50,64) of im2col for ALL rows (avoid NaN garbage into valid cols)
  for (int s = tid; s < 144 * 7; s += 512) {
    int jt = s / 7, d = s - jt * 7;
    *reinterpret_cast<unsigned*>(&sIm[jt * 72 + 50 + 2 * d]) = 0u;
  }
  __syncthreads();
  // build im2col rows jt in [0,132): B[ck=k*10+c][jt] = feats[c][t0-4+jt+k] * 2^-6
  for (int s = tid; s < 660; s += 512) {
    int jt = s / 5, k = s - jt * 5;
#pragma unroll
    for (int c = 0; c < 10; ++c)
      sIm[jt * 72 + k * 10 + c] = (_Float16)(sF[c * 136 + jt + k] * 0.015625f);
  }
  __syncthreads();

  // ---- phase 1: conv1 (M=64, N=132(+pad), K=64) ----
  half8 a1[4][2];
#pragma unroll
  for (int m = 0; m < 4; ++m)
#pragma unroll
    for (int kk = 0; kk < 2; ++kk) a1[m][kk] = w1f[(m * 2 + kk) * 64 + lane];

  for (int n0 = w; n0 < 9; n0 += 8) {  // wave w -> n-tile w; wave 0 also takes tile 8
    int jt = n0 * 16 + ln;
    half8 bf0 = *reinterpret_cast<const half8*>(&sIm[jt * 72 + qd * 8]);
    half8 bf1 = *reinterpret_cast<const half8*>(&sIm[jt * 72 + 32 + qd * 8]);
#pragma unroll
    for (int m = 0; m < 4; ++m) {
      f32x4 acc;
      f32x4 bv = *reinterpret_cast<const f32x4*>(&b1g[m * 16 + qd * 4]);
#pragma unroll
      for (int r = 0; r < 4; ++r) acc[r] = bv[r] * 0.015625f;  // bias * 2^-6
      acc = __builtin_amdgcn_mfma_f32_16x16x32_f16(a1[m][0], bf0, acc, 0, 0, 0);
      acc = __builtin_amdgcn_mfma_f32_16x16x32_f16(a1[m][1], bf1, acc, 0, 0, 0);
      if (jt < 132) {
        int t = t0 - 2 + jt;
        bool inr = (t >= 0 && t < T_);
        half4 hv;
#pragma unroll
        for (int r = 0; r < 4; ++r) {
          float h = inr ? gelu_exact(acc[r] * 64.f) * 0.0625f : 0.f;  // h1 * 2^-4
          hv[r] = (_Float16)h;
        }
        *reinterpret_cast<half4*>(&sH1[jt * 72 + m * 16 + qd * 4]) = hv;
      }
    }
  }
  __syncthreads();

  // ---- phase 2: conv2 as 5 shifted GEMMs; wave = (m-pair p, n-pair nq) ----
  int p = w & 1, nq = w >> 1;
  f32x4 acc2[2][2];
#pragma unroll
  for (int dm = 0; dm < 2; ++dm) {
    f32x4 bv = *reinterpret_cast<const f32x4*>(&b2g[(2 * p + dm) * 16 + qd * 4]);
#pragma unroll
    for (int dn = 0; dn < 2; ++dn)
#pragma unroll
      for (int r = 0; r < 4; ++r) acc2[dm][dn][r] = bv[r] * 0.0625f;  // bias * 2^-4
  }
#pragma unroll
  for (int k = 0; k < 5; ++k) {
#pragma unroll
    for (int kk = 0; kk < 2; ++kk) {
      half8 A0 = w2f[((k * 2 + kk) * 4 + 2 * p + 0) * 64 + lane];
      half8 A1 = w2f[((k * 2 + kk) * 4 + 2 * p + 1) * 64 + lane];
      half8 B0 = *reinterpret_cast<const half8*>(
          &sH1[((2 * nq + 0) * 16 + ln + k) * 72 + kk * 32 + qd * 8]);
      half8 B1 = *reinterpret_cast<const half8*>(
          &sH1[((2 * nq + 1) * 16 + ln + k) * 72 + kk * 32 + qd * 8]);
      acc2[0][0] = __builtin_amdgcn_mfma_f32_16x16x32_f16(A0, B0, acc2[0][0], 0, 0, 0);
      acc2[0][1] = __builtin_amdgcn_mfma_f32_16x16x32_f16(A0, B1, acc2[0][1], 0, 0, 0);
      acc2[1][0] = __builtin_amdgcn_mfma_f32_16x16x32_f16(A1, B0, acc2[1][0], 0, 0, 0);
      acc2[1][1] = __builtin_amdgcn_mfma_f32_16x16x32_f16(A1, B1, acc2[1][1], 0, 0, 0);
    }
  }
  // ---- conv3 + sigmoid epilogue ----
  f32x4 w3a = *reinterpret_cast<const f32x4*>(&w3g[(2 * p + 0) * 16 + qd * 4]);
  f32x4 w3b = *reinterpret_cast<const f32x4*>(&w3g[(2 * p + 1) * 16 + qd * 4]);
#pragma unroll
  for (int dn = 0; dn < 2; ++dn) {
    float s = 0.f;
#pragma unroll
    for (int r = 0; r < 4; ++r) s += w3a[r] * gelu_exact(acc2[0][dn][r] * 16.f);
#pragma unroll
    for (int r = 0; r < 4; ++r) s += w3b[r] * gelu_exact(acc2[1][dn][r] * 16.f);
    s += __shfl_xor(s, 16);
    s += __shfl_xor(s, 32);
    if (lane < 16) sPart[p][(2 * nq + dn) * 16 + lane] = s;
  }
  __syncthreads();
  if (tid < 128) {
    int t = t0 + tid;
    float logit = sPart[0][tid] + sPart[1][tid] + b3g[0];
    float m = amask[(size_t)b * T_ + t];
    lp[(size_t)b * T_ + t] = (1.f / (1.f + expf(-logit))) * m;
  }
}

// ---------------- Kernel D: smooth learned + blend (unchanged) ----------------
__global__ __launch_bounds__(256)
void final_k(const float* __restrict__ rule, const float* __restrict__ lp,
             const float* __restrict__ amask, float* __restrict__ out) {
  int idx = blockIdx.x * 256 + threadIdx.x;
  if (idx >= BT) return;
  int t = idx & (T_ - 1);
  float s = 0.f;
#pragma unroll
  for (int d = -2; d <= 2; ++d) {
    int tt = t + d;
    if (tt >= 0 && tt < T_) s += lp[idx + d];
  }
  float m = amask[idx];
  float learned = clip01(s * 0.2f * m);
  out[idx] = clip01(0.5f * rule[idx] + 0.5f * learned) * m;
}

}  // namespace

extern "C" void kernel_launch(void* const* d_in, const int* in_sizes, int n_in,
                              void* d_out, int out_size, void* d_ws, size_t ws_size,
                              hipStream_t stream) {
  const float* traj      = (const float*)d_in[0];
  const float* intervals = (const float*)d_in[1];
  const float* amask     = (const float*)d_in[2];
  const float* omask     = (const float*)d_in[3];
  const float* w1        = (const float*)d_in[4];
  const float* b1        = (const float*)d_in[5];
  const float* w2        = (const float*)d_in[6];
  const float* b2        = (const float*)d_in[7];
  const float* w3        = (const float*)d_in[8];
  const float* b3        = (const float*)d_in[9];
  float* out = (float*)d_out;
  float* ws = (float*)d_ws;

  float* feats = ws + OFF_FEATS;
  float* hc   = ws + OFF_HC;
  float* an   = ws + OFF_AN;
  float* sc   = ws + OFF_SC;
  float* ot   = ws + OFF_OT;
  float* rule = ws + OFF_RULE;
  float* lp   = ws + OFF_LP;
  half8* w1f = (half8*)(ws + OFF_W1F);
  half8* w2f = (half8*)(ws + OFF_W2F);

  featurize_k<<<BT / 256, 256, 0, stream>>>(traj, intervals, amask, omask,
                                            feats, hc, an, sc, ot);
  rule_k<<<B_, 256, 0, stream>>>(hc, an, sc, ot, amask, rule);
  // repack AFTER rule_k (frags overwrite the dead hc region), BEFORE conv
  repack_k<<<12, 256, 0, stream>>>(w1, w2, w1f, w2f);
  conv_k<<<dim3(T_ / TTILE, B_), 512, 0, stream>>>(feats, w1f, b1, w2f, b2, w3, b3, amask, lp);
  final_k<<<BT / 256, 256, 0, stream>>>(rule, lp, amask, out);
}

// Round 3
// 205.669 us; speedup vs baseline: 4.3314x; 1.5002x over previous
//
#include <hip/hip_runtime.h>

namespace {

constexpr int B_ = 128;
constexpr int T_ = 4096;
constexpr int BT = B_ * T_;
constexpr int TTILE = 128;
constexpr unsigned INFBITS = 0x7F800000u;

// workspace layout (float offsets); footprint 32 MB
constexpr size_t OFF_FEATS = 0;
constexpr size_t OFF_HC   = (size_t)B_ * 10 * T_;          // 5,242,880
constexpr size_t OFF_AN   = OFF_HC + (size_t)BT;
constexpr size_t OFF_SC   = OFF_AN + (size_t)BT;
constexpr size_t OFF_OT   = OFF_SC + (size_t)BT;
constexpr size_t OFF_RULE = OFF_OT + (size_t)BT;
constexpr size_t OFF_LP   = OFF_RULE + (size_t)BT;
// weight fragments live in the hc region (dead after rule2_k, stream-ordered)
constexpr size_t OFF_W1F  = OFF_HC;
constexpr size_t OFF_W2F  = OFF_HC + 2048;
// scales[3*B] parked at start of lp region: written by scale_k, read by rule2_k,
// then conv_k overwrites lp afterwards (stream-ordered, no conflict)
constexpr size_t OFF_SCALES = OFF_LP;

typedef _Float16 half8 __attribute__((ext_vector_type(8)));
typedef _Float16 half4 __attribute__((ext_vector_type(4)));
typedef float f32x4 __attribute__((ext_vector_type(4)));

__device__ __forceinline__ float gelu_exact(float x) {
  return 0.5f * x * (1.0f + erff(x * 0.7071067811865475f));
}
__device__ __forceinline__ float clip01(float x) { return fminf(fmaxf(x, 0.f), 1.f); }

// ---------------- Kernel A: featurize (unchanged) ----------------
__global__ __launch_bounds__(256)
void featurize_k(const float* __restrict__ traj, const float* __restrict__ intervals,
                 const float* __restrict__ amask, const float* __restrict__ omask,
                 float* __restrict__ feats, float* __restrict__ hc, float* __restrict__ an,
                 float* __restrict__ sc, float* __restrict__ ot) {
  int idx = blockIdx.x * 256 + threadIdx.x;
  if (idx >= BT) return;
  int b = idx >> 12;
  int t = idx & (T_ - 1);
  const float* tr = traj + (size_t)b * T_ * 2;
  const float* iv = intervals + (size_t)b * T_;
  const float* mk = amask + (size_t)b * T_;
  const float* om = omask + (size_t)b * T_;
  float m  = mk[t];
  float m1 = (t >= 1) ? mk[t - 1] : 0.f;
  float m2 = (t >= 2) ? mk[t - 2] : 0.f;
  float pm01 = (m > 0.5f && m1 > 0.5f) ? 1.f : 0.f;
  float pm12 = (m1 > 0.5f && m2 > 0.5f) ? 1.f : 0.f;
  float x0x = tr[2 * t] * m, x0y = tr[2 * t + 1] * m;
  float x1x = 0.f, x1y = 0.f, x2x = 0.f, x2y = 0.f;
  if (t >= 1) { x1x = tr[2 * (t - 1)] * m1; x1y = tr[2 * (t - 1) + 1] * m1; }
  if (t >= 2) { x2x = tr[2 * (t - 2)] * m2; x2y = tr[2 * (t - 2) + 1] * m2; }
  float dt0 = fmaxf(iv[t], 1e-3f);
  float dt1 = (t >= 1) ? fmaxf(iv[t - 1], 1e-3f) : 1e-3f;
  float vx = 0.f, vy = 0.f, v1x = 0.f, v1y = 0.f;
  if (t >= 1) { vx = (x0x - x1x) * pm01 / dt0 * m; vy = (x0y - x1y) * pm01 / dt0 * m; }
  if (t >= 2) { v1x = (x1x - x2x) * pm12 / dt1 * m1; v1y = (x1y - x2y) * pm12 / dt1 * m1; }
  float ax = 0.f, ay = 0.f;
  if (t >= 1) { ax = (vx - v1x) * pm01 / dt0 * m; ay = (vy - v1y) * pm01 / dt0 * m; }
  float s2 = vx * vx + vy * vy;
  float speed = (s2 > 0.f ? sqrtf(s2) : 0.f) * m;
  float s21 = v1x * v1x + v1y * v1y;
  float speed1 = (s21 > 0.f ? sqrtf(s21) : 0.f) * m1;
  float scv = (t >= 1) ? fabsf((speed - speed1) * pm01) * m : 0.f;
  float a2 = ax * ax + ay * ay;
  float anv = (a2 > 0.f ? sqrtf(a2) : 0.f) * m;
  float hcv = 0.f;
  if (t >= 1) {
    float h0 = atan2f(vy, vx), h1 = atan2f(v1y, v1x);
    float d = h0 - h1;
    hcv = fabsf(atan2f(sinf(d), cosf(d))) * pm01 * m;
  }
  float obs = om[t] * m;
  float otv = (t >= 1) ? fminf(fabsf(om[t] - om[t - 1]) * pm01 * m, 1.f) : 0.f;
  float itf = iv[t] * m;
  size_t fb = (size_t)b * 10 * T_ + t;
  feats[fb + 0 * T_] = x0x; feats[fb + 1 * T_] = x0y;
  feats[fb + 2 * T_] = vx;  feats[fb + 3 * T_] = vy;
  feats[fb + 4 * T_] = ax;  feats[fb + 5 * T_] = ay;
  feats[fb + 6 * T_] = speed; feats[fb + 7 * T_] = hcv;
  feats[fb + 8 * T_] = itf;   feats[fb + 9 * T_] = obs;
  hc[idx] = hcv; an[idx] = anv; sc[idx] = scv; ot[idx] = otv;
}

// ---------------- parallel bucket find ----------------
// hist has CHUNK*256 bins. Finds bin s.t. cum(<bin) <= k < cum(<=bin).
// Winner writes *selb = bin, *selk = k - cum(<bin). 2 __syncthreads.
template <int CHUNK>
__device__ __forceinline__ void find_bucket_par(const unsigned* __restrict__ hist,
                                                unsigned* selb, unsigned* selk,
                                                unsigned* sW4, int tid) {
  unsigned k = *selk;  // stable: set before the barrier preceding this call
  unsigned vals[CHUNK];
  unsigned ps = 0;
#pragma unroll
  for (int c = 0; c < CHUNK; ++c) { vals[c] = hist[tid * CHUNK + c]; ps += vals[c]; }
  unsigned incl = ps;
  int lane = tid & 63;
#pragma unroll
  for (int off = 1; off < 64; off <<= 1) {
    unsigned tv = __shfl_up(incl, off, 64);
    if (lane >= off) incl += tv;
  }
  if (lane == 63) sW4[tid >> 6] = incl;
  __syncthreads();
  int wv = tid >> 6;
  unsigned woff = 0;
  if (wv > 0) woff += sW4[0];
  if (wv > 1) woff += sW4[1];
  if (wv > 2) woff += sW4[2];
  incl += woff;
  unsigned excl = incl - ps;
  __syncthreads();  // all reads of *selk / sW4 complete before winner writes
  if (excl <= k && k < incl) {
    unsigned run = excl;
    int c = 0;
#pragma unroll
    for (; c < CHUNK - 1; ++c) {
      if (run + vals[c] > k) break;
      run += vals[c];
    }
    *selb = (unsigned)(tid * CHUNK + c);
    *selk = k - run;
  }
  __syncthreads();
}

// exact k-th smallest (by float bits; all candidates >= +0, invalid = +inf)
__device__ __forceinline__ float radix_select(const unsigned* u, unsigned k, unsigned* hist,
                                              unsigned* selb, unsigned* selk,
                                              unsigned* sW4, int tid) {
  for (int i = tid; i < 4096; i += 256) hist[i] = 0u;
  if (tid == 0) *selk = k;
  __syncthreads();
#pragma unroll
  for (int r = 0; r < 16; ++r) atomicAdd(&hist[u[r] >> 20], 1u);
  __syncthreads();
  find_bucket_par<16>(hist, selb, selk, sW4, tid);
  unsigned p1 = *selb;
  for (int i = tid; i < 4096; i += 256) hist[i] = 0u;
  __syncthreads();
#pragma unroll
  for (int r = 0; r < 16; ++r)
    if ((u[r] >> 20) == p1) atomicAdd(&hist[(u[r] >> 8) & 0xFFFu], 1u);
  __syncthreads();
  find_bucket_par<16>(hist, selb, selk, sW4, tid);
  unsigned p2 = *selb;
  unsigned pref = (p1 << 12) | p2;
  for (int i = tid; i < 256; i += 256) hist[i] = 0u;
  __syncthreads();
#pragma unroll
  for (int r = 0; r < 16; ++r)
    if ((u[r] >> 8) == pref) atomicAdd(&hist[u[r] & 0xFFu], 1u);
  __syncthreads();
  find_bucket_par<1>(hist, selb, selk, sW4, tid);
  unsigned p3 = *selb;
  __syncthreads();
  return __uint_as_float((p1 << 20) | (p2 << 8) | p3);
}

__device__ __forceinline__ float block_max(float v, float* s4, int tid) {
#pragma unroll
  for (int off = 32; off; off >>= 1) v = fmaxf(v, __shfl_xor(v, off));
  if ((tid & 63) == 0) s4[tid >> 6] = v;
  __syncthreads();
  v = fmaxf(fmaxf(s4[0], s4[1]), fmaxf(s4[2], s4[3]));
  __syncthreads();
  return v;
}

__device__ __forceinline__ int count_valid(const float* mrow, float* mreg, int* i4, int tid) {
  int cnt = 0;
#pragma unroll
  for (int r = 0; r < 16; ++r) { mreg[r] = mrow[tid + 256 * r]; cnt += (mreg[r] > 0.5f); }
#pragma unroll
  for (int off = 32; off; off >>= 1) cnt += __shfl_xor(cnt, off);
  if ((tid & 63) == 0) i4[tid >> 6] = cnt;
  __syncthreads();
  int n = i4[0] + i4[1] + i4[2] + i4[3];
  __syncthreads();
  return n;
}

__device__ __forceinline__ int kth_index(int n) {
  int cidx = (int)ceilf((float)n * 0.95f);
  if (cidx < 1) cidx = 1;
  int kidx = cidx - 1;
  if (kidx < 0) kidx = 0;
  if (kidx > T_ - 1) kidx = T_ - 1;
  return kidx;
}

// ---------------- Kernel B1: per-(row,metric) percentile scale ----------------
__global__ __launch_bounds__(256)
void scale_k(const float* __restrict__ hc, const float* __restrict__ an,
             const float* __restrict__ sc, const float* __restrict__ amask,
             float* __restrict__ scales) {
  __shared__ unsigned hist[4096];
  __shared__ unsigned sW4[4];
  __shared__ unsigned selb, selk;
  __shared__ float s4[4];
  __shared__ int i4[4];
  int b = blockIdx.x, metric = blockIdx.y, tid = threadIdx.x;
  const float* mrow = amask + (size_t)b * T_;
  float mreg[16];
  int n = count_valid(mrow, mreg, i4, tid);
  int kidx = kth_index(n);
  const float* arr = (metric == 0 ? hc : metric == 1 ? an : sc) + (size_t)b * T_;
  unsigned u[16];
  float mx = 0.f;
#pragma unroll
  for (int r = 0; r < 16; ++r) {
    float v = arr[tid + 256 * r];
    if (mreg[r] > 0.5f) {
      mx = fmaxf(mx, fabsf(v));
      unsigned ub = __float_as_uint(v);
      if ((int)ub < 0) ub = 0u;  // -0.0 safety
      u[r] = ub;
    } else u[r] = INFBITS;
  }
  mx = block_max(mx, s4, tid);
  float kth = fabsf(radix_select(u, (unsigned)kidx, hist, &selb, &selk, sW4, tid));
  if (tid == 0) {
    float s = (kth < 1e-6f) ? mx : kth;
    scales[metric * B_ + b] = fmaxf(s, 1e-6f);
  }
}

// ---------------- Kernel B2: scores + smooth + 4th select + normalize ----------------
__global__ __launch_bounds__(256)
void rule2_k(const float* __restrict__ hc, const float* __restrict__ an,
             const float* __restrict__ sc, const float* __restrict__ ot,
             const float* __restrict__ amask, const float* __restrict__ scales,
             float* __restrict__ rule) {
  __shared__ unsigned hist[4096];
  __shared__ unsigned sW4[4];
  __shared__ unsigned selb, selk;
  __shared__ float vbuf[4096];
  __shared__ float s4[4];
  __shared__ int i4[4];
  int b = blockIdx.x, tid = threadIdx.x;
  const float* mrow = amask + (size_t)b * T_;
  float mreg[16];
  int n = count_valid(mrow, mreg, i4, tid);
  int kidx = kth_index(n);
  float sc0 = scales[0 * B_ + b], sc1 = scales[1 * B_ + b], sc2 = scales[2 * B_ + b];
  const float* hrow = hc + (size_t)b * T_;
  const float* arow = an + (size_t)b * T_;
  const float* srow = sc + (size_t)b * T_;
  const float* otrow = ot + (size_t)b * T_;
#pragma unroll
  for (int r = 0; r < 16; ++r) {
    int t = tid + 256 * r;
    float v = 0.f;
    if (n > 0) {
      v = 0.35f * (hrow[t] / sc0) + 0.30f * (arow[t] / sc1)
        + 0.25f * (srow[t] / sc2) + 0.10f * otrow[t];
    }
    vbuf[t] = v;
  }
  __syncthreads();
  float sm[16];
#pragma unroll
  for (int r = 0; r < 16; ++r) {
    int t = tid + 256 * r;
    float s = 0.f;
#pragma unroll
    for (int d = -2; d <= 2; ++d) {
      int tt = t + d;
      if (tt >= 0 && tt < T_) s += vbuf[tt];
    }
    sm[r] = s * 0.2f * mreg[r];
  }
  unsigned u2[16];
  float mx2 = 0.f;
#pragma unroll
  for (int r = 0; r < 16; ++r) {
    if (mreg[r] > 0.5f) {
      mx2 = fmaxf(mx2, fabsf(sm[r]));
      unsigned ub = __float_as_uint(sm[r]);
      if ((int)ub < 0) ub = 0u;
      u2[r] = ub;
    } else u2[r] = INFBITS;
  }
  mx2 = block_max(mx2, s4, tid);
  float kth4 = fabsf(radix_select(u2, (unsigned)kidx, hist, &selb, &selk, sW4, tid));
  float scale4 = fmaxf((kth4 < 1e-6f) ? mx2 : kth4, 1e-6f);
  float* rrow = rule + (size_t)b * T_;
#pragma unroll
  for (int r = 0; r < 16; ++r) {
    int t = tid + 256 * r;
    float v = (n > 0) ? sm[r] / scale4 : 0.f;
    rrow[t] = clip01(v) * mreg[r];
  }
}

// ---------------- weight repack (unchanged) ----------------
__global__ __launch_bounds__(256)
void repack_k(const float* __restrict__ w1g, const float* __restrict__ w2g,
              half8* __restrict__ w1f, half8* __restrict__ w2f) {
  int gid = blockIdx.x * 256 + threadIdx.x;
  if (gid >= 48 * 64) return;
  int fid = gid >> 6, lane = gid & 63;
  int qd = lane >> 4, ln = lane & 15;
  half8 v;
  if (fid < 8) {
    int m = fid >> 1, kk = fid & 1;
    int o = m * 16 + ln;
#pragma unroll
    for (int j = 0; j < 8; ++j) {
      int ck = kk * 32 + qd * 8 + j;
      float val = 0.f;
      if (ck < 50) { int k_ = ck / 10, c = ck - 10 * k_; val = w1g[o * 50 + c * 5 + k_]; }
      v[j] = (_Float16)val;
    }
    w1f[fid * 64 + lane] = v;
  } else {
    int f2 = fid - 8;
    int k = f2 >> 3, kk = (f2 >> 2) & 1, m = f2 & 3;
    int o = m * 16 + ln;
#pragma unroll
    for (int j = 0; j < 8; ++j) {
      int ic = kk * 32 + qd * 8 + j;
      v[j] = (_Float16)w2g[o * 320 + ic * 5 + k];
    }
    w2f[f2 * 64 + lane] = v;
  }
}

// ---------------- Kernel C: MFMA conv stack (unchanged) ----------------
__global__ __launch_bounds__(512, 4)
void conv_k(const float* __restrict__ feats, const half8* __restrict__ w1f,
            const float* __restrict__ b1g, const half8* __restrict__ w2f,
            const float* __restrict__ b2g, const float* __restrict__ w3g,
            const float* __restrict__ b3g, const float* __restrict__ amask,
            float* __restrict__ lp) {
  __shared__ _Float16 sIm[144 * 72];
  __shared__ _Float16 sH1[132 * 72];
  __shared__ float sF[10 * 136];
  __shared__ float sPart[2][128];
  int tid = threadIdx.x;
  int lane = tid & 63, w = tid >> 6;
  int qd = lane >> 4, ln = lane & 15;
  int tile = blockIdx.x, b = blockIdx.y;
  int t0 = tile * TTILE;
  const float* frow = feats + (size_t)b * 10 * T_;

  for (int s = tid; s < 1360; s += 512) {
    int c = s / 136, u = s - c * 136;
    int t = t0 - 4 + u;
    sF[s] = (t >= 0 && t < T_) ? frow[(size_t)c * T_ + t] : 0.f;
  }
  for (int s = tid; s < 144 * 7; s += 512) {
    int jt = s / 7, d = s - jt * 7;
    *reinterpret_cast<unsigned*>(&sIm[jt * 72 + 50 + 2 * d]) = 0u;
  }
  __syncthreads();
  for (int s = tid; s < 660; s += 512) {
    int jt = s / 5, k = s - jt * 5;
#pragma unroll
    for (int c = 0; c < 10; ++c)
      sIm[jt * 72 + k * 10 + c] = (_Float16)(sF[c * 136 + jt + k] * 0.015625f);
  }
  __syncthreads();

  half8 a1[4][2];
#pragma unroll
  for (int m = 0; m < 4; ++m)
#pragma unroll
    for (int kk = 0; kk < 2; ++kk) a1[m][kk] = w1f[(m * 2 + kk) * 64 + lane];

  for (int n0 = w; n0 < 9; n0 += 8) {
    int jt = n0 * 16 + ln;
    half8 bf0 = *reinterpret_cast<const half8*>(&sIm[jt * 72 + qd * 8]);
    half8 bf1 = *reinterpret_cast<const half8*>(&sIm[jt * 72 + 32 + qd * 8]);
#pragma unroll
    for (int m = 0; m < 4; ++m) {
      f32x4 acc;
      f32x4 bv = *reinterpret_cast<const f32x4*>(&b1g[m * 16 + qd * 4]);
#pragma unroll
      for (int r = 0; r < 4; ++r) acc[r] = bv[r] * 0.015625f;
      acc = __builtin_amdgcn_mfma_f32_16x16x32_f16(a1[m][0], bf0, acc, 0, 0, 0);
      acc = __builtin_amdgcn_mfma_f32_16x16x32_f16(a1[m][1], bf1, acc, 0, 0, 0);
      if (jt < 132) {
        int t = t0 - 2 + jt;
        bool inr = (t >= 0 && t < T_);
        half4 hv;
#pragma unroll
        for (int r = 0; r < 4; ++r) {
          float h = inr ? gelu_exact(acc[r] * 64.f) * 0.0625f : 0.f;
          hv[r] = (_Float16)h;
        }
        *reinterpret_cast<half4*>(&sH1[jt * 72 + m * 16 + qd * 4]) = hv;
      }
    }
  }
  __syncthreads();

  int p = w & 1, nq = w >> 1;
  f32x4 acc2[2][2];
#pragma unroll
  for (int dm = 0; dm < 2; ++dm) {
    f32x4 bv = *reinterpret_cast<const f32x4*>(&b2g[(2 * p + dm) * 16 + qd * 4]);
#pragma unroll
    for (int dn = 0; dn < 2; ++dn)
#pragma unroll
      for (int r = 0; r < 4; ++r) acc2[dm][dn][r] = bv[r] * 0.0625f;
  }
#pragma unroll
  for (int k = 0; k < 5; ++k) {
#pragma unroll
    for (int kk = 0; kk < 2; ++kk) {
      half8 A0 = w2f[((k * 2 + kk) * 4 + 2 * p + 0) * 64 + lane];
      half8 A1 = w2f[((k * 2 + kk) * 4 + 2 * p + 1) * 64 + lane];
      half8 B0 = *reinterpret_cast<const half8*>(
          &sH1[((2 * nq + 0) * 16 + ln + k) * 72 + kk * 32 + qd * 8]);
      half8 B1 = *reinterpret_cast<const half8*>(
          &sH1[((2 * nq + 1) * 16 + ln + k) * 72 + kk * 32 + qd * 8]);
      acc2[0][0] = __builtin_amdgcn_mfma_f32_16x16x32_f16(A0, B0, acc2[0][0], 0, 0, 0);
      acc2[0][1] = __builtin_amdgcn_mfma_f32_16x16x32_f16(A0, B1, acc2[0][1], 0, 0, 0);
      acc2[1][0] = __builtin_amdgcn_mfma_f32_16x16x32_f16(A1, B0, acc2[1][0], 0, 0, 0);
      acc2[1][1] = __builtin_amdgcn_mfma_f32_16x16x32_f16(A1, B1, acc2[1][1], 0, 0, 0);
    }
  }
  f32x4 w3a = *reinterpret_cast<const f32x4*>(&w3g[(2 * p + 0) * 16 + qd * 4]);
  f32x4 w3b = *reinterpret_cast<const f32x4*>(&w3g[(2 * p + 1) * 16 + qd * 4]);
#pragma unroll
  for (int dn = 0; dn < 2; ++dn) {
    float s = 0.f;
#pragma unroll
    for (int r = 0; r < 4; ++r) s += w3a[r] * gelu_exact(acc2[0][dn][r] * 16.f);
#pragma unroll
    for (int r = 0; r < 4; ++r) s += w3b[r] * gelu_exact(acc2[1][dn][r] * 16.f);
    s += __shfl_xor(s, 16);
    s += __shfl_xor(s, 32);
    if (lane < 16) sPart[p][(2 * nq + dn) * 16 + lane] = s;
  }
  __syncthreads();
  if (tid < 128) {
    int t = t0 + tid;
    float logit = sPart[0][tid] + sPart[1][tid] + b3g[0];
    float m = amask[(size_t)b * T_ + t];
    lp[(size_t)b * T_ + t] = (1.f / (1.f + expf(-logit))) * m;
  }
}

// ---------------- Kernel D: smooth learned + blend (unchanged) ----------------
__global__ __launch_bounds__(256)
void final_k(const float* __restrict__ rule, const float* __restrict__ lp,
             const float* __restrict__ amask, float* __restrict__ out) {
  int idx = blockIdx.x * 256 + threadIdx.x;
  if (idx >= BT) return;
  int t = idx & (T_ - 1);
  float s = 0.f;
#pragma unroll
  for (int d = -2; d <= 2; ++d) {
    int tt = t + d;
    if (tt >= 0 && tt < T_) s += lp[idx + d];
  }
  float m = amask[idx];
  float learned = clip01(s * 0.2f * m);
  out[idx] = clip01(0.5f * rule[idx] + 0.5f * learned) * m;
}

}  // namespace

extern "C" void kernel_launch(void* const* d_in, const int* in_sizes, int n_in,
                              void* d_out, int out_size, void* d_ws, size_t ws_size,
                              hipStream_t stream) {
  const float* traj      = (const float*)d_in[0];
  const float* intervals = (const float*)d_in[1];
  const float* amask     = (const float*)d_in[2];
  const float* omask     = (const float*)d_in[3];
  const float* w1        = (const float*)d_in[4];
  const float* b1        = (const float*)d_in[5];
  const float* w2        = (const float*)d_in[6];
  const float* b2        = (const float*)d_in[7];
  const float* w3        = (const float*)d_in[8];
  const float* b3        = (const float*)d_in[9];
  float* out = (float*)d_out;
  float* ws = (float*)d_ws;

  float* feats = ws + OFF_FEATS;
  float* hc   = ws + OFF_HC;
  float* an   = ws + OFF_AN;
  float* sc   = ws + OFF_SC;
  float* ot   = ws + OFF_OT;
  float* rule = ws + OFF_RULE;
  float* lp   = ws + OFF_LP;
  float* scales = ws + OFF_SCALES;  // lp region start; consumed before conv_k writes lp
  half8* w1f = (half8*)(ws + OFF_W1F);
  half8* w2f = (half8*)(ws + OFF_W2F);

  featurize_k<<<BT / 256, 256, 0, stream>>>(traj, intervals, amask, omask,
                                            feats, hc, an, sc, ot);
  scale_k<<<dim3(B_, 3), 256, 0, stream>>>(hc, an, sc, amask, scales);
  rule2_k<<<B_, 256, 0, stream>>>(hc, an, sc, ot, amask, scales, rule);
  // repack AFTER rule2_k (frags overwrite the dead hc region), BEFORE conv
  repack_k<<<12, 256, 0, stream>>>(w1, w2, w1f, w2f);
  conv_k<<<dim3(T_ / TTILE, B_), 512, 0, stream>>>(feats, w1f, b1, w2f, b2, w3, b3, amask, lp);
  final_k<<<BT / 256, 256, 0, stream>>>(rule, lp, amask, out);
}

// Round 4
// 189.715 us; speedup vs baseline: 4.6956x; 1.0841x over previous
//
#include <hip/hip_runtime.h>

namespace {

constexpr int B_ = 128;
constexpr int T_ = 4096;
constexpr int BT = B_ * T_;
constexpr int TTILE = 128;
constexpr unsigned INFBITS = 0x7F800000u;

// workspace layout (float offsets); footprint 32 MB
constexpr size_t OFF_FEATS = 0;
constexpr size_t OFF_HC   = (size_t)B_ * 10 * T_;          // 5,242,880
constexpr size_t OFF_AN   = OFF_HC + (size_t)BT;
constexpr size_t OFF_SC   = OFF_AN + (size_t)BT;
constexpr size_t OFF_OT   = OFF_SC + (size_t)BT;
constexpr size_t OFF_RULE = OFF_OT + (size_t)BT;
constexpr size_t OFF_LP   = OFF_RULE + (size_t)BT;
constexpr size_t OFF_W1F  = OFF_HC;            // dead hc region after rule2_k
constexpr size_t OFF_W2F  = OFF_HC + 2048;
constexpr size_t OFF_SCALES = OFF_LP;          // consumed before conv_k writes lp

typedef _Float16 half8 __attribute__((ext_vector_type(8)));
typedef _Float16 half4 __attribute__((ext_vector_type(4)));
typedef _Float16 half2_t __attribute__((ext_vector_type(2)));
typedef float f32x4 __attribute__((ext_vector_type(4)));

__device__ __forceinline__ float clip01(float x) { return fminf(fmaxf(x, 0.f), 1.f); }

// branchless GELU via Abramowitz-Stegun 7.1.26 erf (|err| <= 1.5e-7)
__device__ __forceinline__ float gelu_fast(float x) {
  float s = x * 0.7071067811865475f;
  float a = fabsf(s);
  float t = __builtin_amdgcn_rcpf(__builtin_fmaf(0.3275911f, a, 1.0f));
  float p = __builtin_fmaf(t, 1.061405429f, -1.453152027f);
  p = __builtin_fmaf(t, p, 1.421413741f);
  p = __builtin_fmaf(t, p, -0.284496736f);
  p = __builtin_fmaf(t, p, 0.254829592f);
  p = p * t;
  float e = __builtin_amdgcn_exp2f(a * a * -1.4426950408889634f);
  float erfa = __builtin_fmaf(-p, e, 1.0f);
  float erfs = copysignf(erfa, s);
  return 0.5f * x * (1.0f + erfs);
}

// ---------------- Kernel A: featurize ----------------
__global__ __launch_bounds__(256)
void featurize_k(const float* __restrict__ traj, const float* __restrict__ intervals,
                 const float* __restrict__ amask, const float* __restrict__ omask,
                 float* __restrict__ feats, float* __restrict__ hc, float* __restrict__ an,
                 float* __restrict__ sc, float* __restrict__ ot) {
  int idx = blockIdx.x * 256 + threadIdx.x;
  if (idx >= BT) return;
  int b = idx >> 12;
  int t = idx & (T_ - 1);
  const float* tr = traj + (size_t)b * T_ * 2;
  const float* iv = intervals + (size_t)b * T_;
  const float* mk = amask + (size_t)b * T_;
  const float* om = omask + (size_t)b * T_;
  float m  = mk[t];
  float m1 = (t >= 1) ? mk[t - 1] : 0.f;
  float m2 = (t >= 2) ? mk[t - 2] : 0.f;
  float pm01 = (m > 0.5f && m1 > 0.5f) ? 1.f : 0.f;
  float pm12 = (m1 > 0.5f && m2 > 0.5f) ? 1.f : 0.f;
  float x0x = tr[2 * t] * m, x0y = tr[2 * t + 1] * m;
  float x1x = 0.f, x1y = 0.f, x2x = 0.f, x2y = 0.f;
  if (t >= 1) { x1x = tr[2 * (t - 1)] * m1; x1y = tr[2 * (t - 1) + 1] * m1; }
  if (t >= 2) { x2x = tr[2 * (t - 2)] * m2; x2y = tr[2 * (t - 2) + 1] * m2; }
  float dt0 = fmaxf(iv[t], 1e-3f);
  float dt1 = (t >= 1) ? fmaxf(iv[t - 1], 1e-3f) : 1e-3f;
  float vx = 0.f, vy = 0.f, v1x = 0.f, v1y = 0.f;
  if (t >= 1) { vx = (x0x - x1x) * pm01 / dt0 * m; vy = (x0y - x1y) * pm01 / dt0 * m; }
  if (t >= 2) { v1x = (x1x - x2x) * pm12 / dt1 * m1; v1y = (x1y - x2y) * pm12 / dt1 * m1; }
  float ax = 0.f, ay = 0.f;
  if (t >= 1) { ax = (vx - v1x) * pm01 / dt0 * m; ay = (vy - v1y) * pm01 / dt0 * m; }
  float s2 = vx * vx + vy * vy;
  float speed = (s2 > 0.f ? sqrtf(s2) : 0.f) * m;
  float s21 = v1x * v1x + v1y * v1y;
  float speed1 = (s21 > 0.f ? sqrtf(s21) : 0.f) * m1;
  float scv = (t >= 1) ? fabsf((speed - speed1) * pm01) * m : 0.f;
  float a2 = ax * ax + ay * ay;
  float anv = (a2 > 0.f ? sqrtf(a2) : 0.f) * m;
  // heading change with ONE atan2: d = h0-h1 -> sin d ~ cross, cos d ~ dot.
  // zero-velocity cases match atan2(0,0)=0 reference semantics exactly:
  //  v1==0: |wrap(h0-0)| = |atan2(vy,vx)|;  v==0: |wrap(-h1)| = |atan2(v1y,v1x)|.
  float hcv = 0.f;
  if (t >= 1) {
    bool z0 = (vx == 0.f && vy == 0.f);
    bool z1 = (v1x == 0.f && v1y == 0.f);
    float yy, xx;
    if (z1)      { yy = vy;  xx = vx; }
    else if (z0) { yy = v1y; xx = v1x; }
    else { yy = vy * v1x - vx * v1y; xx = vx * v1x + vy * v1y; }
    hcv = fabsf(atan2f(yy, xx)) * pm01 * m;
  }
  float obs = om[t] * m;
  float otv = (t >= 1) ? fminf(fabsf(om[t] - om[t - 1]) * pm01 * m, 1.f) : 0.f;
  float itf = iv[t] * m;
  size_t fb = (size_t)b * 10 * T_ + t;
  feats[fb + 0 * T_] = x0x; feats[fb + 1 * T_] = x0y;
  feats[fb + 2 * T_] = vx;  feats[fb + 3 * T_] = vy;
  feats[fb + 4 * T_] = ax;  feats[fb + 5 * T_] = ay;
  feats[fb + 6 * T_] = speed; feats[fb + 7 * T_] = hcv;
  feats[fb + 8 * T_] = itf;   feats[fb + 9 * T_] = obs;
  hc[idx] = hcv; an[idx] = anv; sc[idx] = scv; ot[idx] = otv;
}

// ---------------- parallel bucket find ----------------
template <int CHUNK>
__device__ __forceinline__ void find_bucket_par(const unsigned* __restrict__ hist,
                                                unsigned* selb, unsigned* selk,
                                                unsigned* sW4, int tid) {
  unsigned k = *selk;
  unsigned vals[CHUNK];
  unsigned ps = 0;
#pragma unroll
  for (int c = 0; c < CHUNK; ++c) { vals[c] = hist[tid * CHUNK + c]; ps += vals[c]; }
  unsigned incl = ps;
  int lane = tid & 63;
#pragma unroll
  for (int off = 1; off < 64; off <<= 1) {
    unsigned tv = __shfl_up(incl, off, 64);
    if (lane >= off) incl += tv;
  }
  if (lane == 63) sW4[tid >> 6] = incl;
  __syncthreads();
  int wv = tid >> 6;
  unsigned woff = 0;
  if (wv > 0) woff += sW4[0];
  if (wv > 1) woff += sW4[1];
  if (wv > 2) woff += sW4[2];
  incl += woff;
  unsigned excl = incl - ps;
  __syncthreads();
  if (excl <= k && k < incl) {
    unsigned run = excl;
    int c = 0;
#pragma unroll
    for (; c < CHUNK - 1; ++c) {
      if (run + vals[c] > k) break;
      run += vals[c];
    }
    *selb = (unsigned)(tid * CHUNK + c);
    *selk = k - run;
  }
  __syncthreads();
}

__device__ __forceinline__ float radix_select(const unsigned* u, unsigned k, unsigned* hist,
                                              unsigned* selb, unsigned* selk,
                                              unsigned* sW4, int tid) {
  for (int i = tid; i < 4096; i += 256) hist[i] = 0u;
  if (tid == 0) *selk = k;
  __syncthreads();
#pragma unroll
  for (int r = 0; r < 16; ++r) atomicAdd(&hist[u[r] >> 20], 1u);
  __syncthreads();
  find_bucket_par<16>(hist, selb, selk, sW4, tid);
  unsigned p1 = *selb;
  for (int i = tid; i < 4096; i += 256) hist[i] = 0u;
  __syncthreads();
#pragma unroll
  for (int r = 0; r < 16; ++r)
    if ((u[r] >> 20) == p1) atomicAdd(&hist[(u[r] >> 8) & 0xFFFu], 1u);
  __syncthreads();
  find_bucket_par<16>(hist, selb, selk, sW4, tid);
  unsigned p2 = *selb;
  unsigned pref = (p1 << 12) | p2;
  for (int i = tid; i < 256; i += 256) hist[i] = 0u;
  __syncthreads();
#pragma unroll
  for (int r = 0; r < 16; ++r)
    if ((u[r] >> 8) == pref) atomicAdd(&hist[u[r] & 0xFFu], 1u);
  __syncthreads();
  find_bucket_par<1>(hist, selb, selk, sW4, tid);
  unsigned p3 = *selb;
  __syncthreads();
  return __uint_as_float((p1 << 20) | (p2 << 8) | p3);
}

__device__ __forceinline__ float block_max(float v, float* s4, int tid) {
#pragma unroll
  for (int off = 32; off; off >>= 1) v = fmaxf(v, __shfl_xor(v, off));
  if ((tid & 63) == 0) s4[tid >> 6] = v;
  __syncthreads();
  v = fmaxf(fmaxf(s4[0], s4[1]), fmaxf(s4[2], s4[3]));
  __syncthreads();
  return v;
}

__device__ __forceinline__ int count_valid(const float* mrow, float* mreg, int* i4, int tid) {
  int cnt = 0;
#pragma unroll
  for (int r = 0; r < 16; ++r) { mreg[r] = mrow[tid + 256 * r]; cnt += (mreg[r] > 0.5f); }
#pragma unroll
  for (int off = 32; off; off >>= 1) cnt += __shfl_xor(cnt, off);
  if ((tid & 63) == 0) i4[tid >> 6] = cnt;
  __syncthreads();
  int n = i4[0] + i4[1] + i4[2] + i4[3];
  __syncthreads();
  return n;
}

__device__ __forceinline__ int kth_index(int n) {
  int cidx = (int)ceilf((float)n * 0.95f);
  if (cidx < 1) cidx = 1;
  int kidx = cidx - 1;
  if (kidx < 0) kidx = 0;
  if (kidx > T_ - 1) kidx = T_ - 1;
  return kidx;
}

// ---------------- Kernel B1: per-(row,metric) percentile scale ----------------
__global__ __launch_bounds__(256)
void scale_k(const float* __restrict__ hc, const float* __restrict__ an,
             const float* __restrict__ sc, const float* __restrict__ amask,
             float* __restrict__ scales) {
  __shared__ unsigned hist[4096];
  __shared__ unsigned sW4[4];
  __shared__ unsigned selb, selk;
  __shared__ float s4[4];
  __shared__ int i4[4];
  int b = blockIdx.x, metric = blockIdx.y, tid = threadIdx.x;
  const float* mrow = amask + (size_t)b * T_;
  float mreg[16];
  int n = count_valid(mrow, mreg, i4, tid);
  int kidx = kth_index(n);
  const float* arr = (metric == 0 ? hc : metric == 1 ? an : sc) + (size_t)b * T_;
  unsigned u[16];
  float mx = 0.f;
#pragma unroll
  for (int r = 0; r < 16; ++r) {
    float v = arr[tid + 256 * r];
    if (mreg[r] > 0.5f) {
      mx = fmaxf(mx, fabsf(v));
      unsigned ub = __float_as_uint(v);
      if ((int)ub < 0) ub = 0u;
      u[r] = ub;
    } else u[r] = INFBITS;
  }
  mx = block_max(mx, s4, tid);
  float kth = fabsf(radix_select(u, (unsigned)kidx, hist, &selb, &selk, sW4, tid));
  if (tid == 0) {
    float s = (kth < 1e-6f) ? mx : kth;
    scales[metric * B_ + b] = fmaxf(s, 1e-6f);
  }
}

// ---------------- Kernel B2: scores + smooth + 4th select + normalize ----------------
__global__ __launch_bounds__(256)
void rule2_k(const float* __restrict__ hc, const float* __restrict__ an,
             const float* __restrict__ sc, const float* __restrict__ ot,
             const float* __restrict__ amask, const float* __restrict__ scales,
             float* __restrict__ rule) {
  __shared__ unsigned hist[4096];
  __shared__ unsigned sW4[4];
  __shared__ unsigned selb, selk;
  __shared__ float vbuf[4096];
  __shared__ float s4[4];
  __shared__ int i4[4];
  int b = blockIdx.x, tid = threadIdx.x;
  const float* mrow = amask + (size_t)b * T_;
  float mreg[16];
  int n = count_valid(mrow, mreg, i4, tid);
  int kidx = kth_index(n);
  float sc0 = scales[0 * B_ + b], sc1 = scales[1 * B_ + b], sc2 = scales[2 * B_ + b];
  const float* hrow = hc + (size_t)b * T_;
  const float* arow = an + (size_t)b * T_;
  const float* srow = sc + (size_t)b * T_;
  const float* otrow = ot + (size_t)b * T_;
#pragma unroll
  for (int r = 0; r < 16; ++r) {
    int t = tid + 256 * r;
    float v = 0.f;
    if (n > 0) {
      v = 0.35f * (hrow[t] / sc0) + 0.30f * (arow[t] / sc1)
        + 0.25f * (srow[t] / sc2) + 0.10f * otrow[t];
    }
    vbuf[t] = v;
  }
  __syncthreads();
  float sm[16];
#pragma unroll
  for (int r = 0; r < 16; ++r) {
    int t = tid + 256 * r;
    float s = 0.f;
#pragma unroll
    for (int d = -2; d <= 2; ++d) {
      int tt = t + d;
      if (tt >= 0 && tt < T_) s += vbuf[tt];
    }
    sm[r] = s * 0.2f * mreg[r];
  }
  unsigned u2[16];
  float mx2 = 0.f;
#pragma unroll
  for (int r = 0; r < 16; ++r) {
    if (mreg[r] > 0.5f) {
      mx2 = fmaxf(mx2, fabsf(sm[r]));
      unsigned ub = __float_as_uint(sm[r]);
      if ((int)ub < 0) ub = 0u;
      u2[r] = ub;
    } else u2[r] = INFBITS;
  }
  mx2 = block_max(mx2, s4, tid);
  float kth4 = fabsf(radix_select(u2, (unsigned)kidx, hist, &selb, &selk, sW4, tid));
  float scale4 = fmaxf((kth4 < 1e-6f) ? mx2 : kth4, 1e-6f);
  float* rrow = rule + (size_t)b * T_;
#pragma unroll
  for (int r = 0; r < 16; ++r) {
    int t = tid + 256 * r;
    float v = (n > 0) ? sm[r] / scale4 : 0.f;
    rrow[t] = clip01(v) * mreg[r];
  }
}

// ---------------- weight repack (unchanged) ----------------
__global__ __launch_bounds__(256)
void repack_k(const float* __restrict__ w1g, const float* __restrict__ w2g,
              half8* __restrict__ w1f, half8* __restrict__ w2f) {
  int gid = blockIdx.x * 256 + threadIdx.x;
  if (gid >= 48 * 64) return;
  int fid = gid >> 6, lane = gid & 63;
  int qd = lane >> 4, ln = lane & 15;
  half8 v;
  if (fid < 8) {
    int m = fid >> 1, kk = fid & 1;
    int o = m * 16 + ln;
#pragma unroll
    for (int j = 0; j < 8; ++j) {
      int ck = kk * 32 + qd * 8 + j;
      float val = 0.f;
      if (ck < 50) { int k_ = ck / 10, c = ck - 10 * k_; val = w1g[o * 50 + c * 5 + k_]; }
      v[j] = (_Float16)val;
    }
    w1f[fid * 64 + lane] = v;
  } else {
    int f2 = fid - 8;
    int k = f2 >> 3, kk = (f2 >> 2) & 1, m = f2 & 3;
    int o = m * 16 + ln;
#pragma unroll
    for (int j = 0; j < 8; ++j) {
      int ic = kk * 32 + qd * 8 + j;
      v[j] = (_Float16)w2g[o * 320 + ic * 5 + k];
    }
    w2f[f2 * 64 + lane] = v;
  }
}

// ---------------- Kernel C: MFMA conv stack ----------------
__global__ __launch_bounds__(512, 4)
void conv_k(const float* __restrict__ feats, const half8* __restrict__ w1f,
            const float* __restrict__ b1g, const half8* __restrict__ w2f,
            const float* __restrict__ b2g, const float* __restrict__ w3g,
            const float* __restrict__ b3g, const float* __restrict__ amask,
            float* __restrict__ lp) {
  __shared__ _Float16 sIm[144 * 72];
  __shared__ _Float16 sH1[132 * 72];
  __shared__ float sF[10 * 136];
  __shared__ float sPart[2][128];
  int tid = threadIdx.x;
  int lane = tid & 63, w = tid >> 6;
  int qd = lane >> 4, ln = lane & 15;
  int tile = blockIdx.x, b = blockIdx.y;
  int t0 = tile * TTILE;
  const float* frow = feats + (size_t)b * 10 * T_;

  // stage fp32 feats tile, pre-scaled by 2^-6 (only consumer is im2col)
  for (int s = tid; s < 1360; s += 512) {
    int c = s / 136, u = s - c * 136;
    int t = t0 - 4 + u;
    sF[s] = (t >= 0 && t < T_) ? frow[(size_t)c * T_ + t] * 0.015625f : 0.f;
  }
  for (int s = tid; s < 144 * 7; s += 512) {
    int jt = s / 7, d = s - jt * 7;
    *reinterpret_cast<unsigned*>(&sIm[jt * 72 + 50 + 2 * d]) = 0u;
  }
  __syncthreads();
  // im2col: B[ck=k*10+c][jt] = feats[c][t0-4+jt+k] * 2^-6, paired half2 stores (RNE)
  for (int s = tid; s < 660; s += 512) {
    int jt = s / 5, k = s - jt * 5;
#pragma unroll
    for (int cp = 0; cp < 5; ++cp) {
      float lo = sF[(2 * cp) * 136 + jt + k];
      float hi = sF[(2 * cp + 1) * 136 + jt + k];
      half2_t pk;
      pk[0] = (_Float16)lo;
      pk[1] = (_Float16)hi;
      *reinterpret_cast<half2_t*>(&sIm[jt * 72 + k * 10 + 2 * cp]) = pk;
    }
  }
  __syncthreads();

  half8 a1[4][2];
#pragma unroll
  for (int m = 0; m < 4; ++m)
#pragma unroll
    for (int kk = 0; kk < 2; ++kk) a1[m][kk] = w1f[(m * 2 + kk) * 64 + lane];

  for (int n0 = w; n0 < 9; n0 += 8) {
    int jt = n0 * 16 + ln;
    half8 bf0 = *reinterpret_cast<const half8*>(&sIm[jt * 72 + qd * 8]);
    half8 bf1 = *reinterpret_cast<const half8*>(&sIm[jt * 72 + 32 + qd * 8]);
#pragma unroll
    for (int m = 0; m < 4; ++m) {
      f32x4 acc;
      f32x4 bv = *reinterpret_cast<const f32x4*>(&b1g[m * 16 + qd * 4]);
#pragma unroll
      for (int r = 0; r < 4; ++r) acc[r] = bv[r] * 0.015625f;
      acc = __builtin_amdgcn_mfma_f32_16x16x32_f16(a1[m][0], bf0, acc, 0, 0, 0);
      acc = __builtin_amdgcn_mfma_f32_16x16x32_f16(a1[m][1], bf1, acc, 0, 0, 0);
      if (jt < 132) {
        int t = t0 - 2 + jt;
        bool inr = (t >= 0 && t < T_);
        half4 hv;
#pragma unroll
        for (int r = 0; r < 4; ++r) {
          float h = inr ? gelu_fast(acc[r] * 64.f) * 0.0625f : 0.f;
          hv[r] = (_Float16)h;
        }
        *reinterpret_cast<half4*>(&sH1[jt * 72 + m * 16 + qd * 4]) = hv;
      }
    }
  }
  __syncthreads();

  int p = w & 1, nq = w >> 1;
  f32x4 acc2[2][2];
#pragma unroll
  for (int dm = 0; dm < 2; ++dm) {
    f32x4 bv = *reinterpret_cast<const f32x4*>(&b2g[(2 * p + dm) * 16 + qd * 4]);
#pragma unroll
    for (int dn = 0; dn < 2; ++dn)
#pragma unroll
      for (int r = 0; r < 4; ++r) acc2[dm][dn][r] = bv[r] * 0.0625f;
  }
#pragma unroll
  for (int k = 0; k < 5; ++k) {
#pragma unroll
    for (int kk = 0; kk < 2; ++kk) {
      half8 A0 = w2f[((k * 2 + kk) * 4 + 2 * p + 0) * 64 + lane];
      half8 A1 = w2f[((k * 2 + kk) * 4 + 2 * p + 1) * 64 + lane];
      half8 B0 = *reinterpret_cast<const half8*>(
          &sH1[((2 * nq + 0) * 16 + ln + k) * 72 + kk * 32 + qd * 8]);
      half8 B1 = *reinterpret_cast<const half8*>(
          &sH1[((2 * nq + 1) * 16 + ln + k) * 72 + kk * 32 + qd * 8]);
      acc2[0][0] = __builtin_amdgcn_mfma_f32_16x16x32_f16(A0, B0, acc2[0][0], 0, 0, 0);
      acc2[0][1] = __builtin_amdgcn_mfma_f32_16x16x32_f16(A0, B1, acc2[0][1], 0, 0, 0);
      acc2[1][0] = __builtin_amdgcn_mfma_f32_16x16x32_f16(A1, B0, acc2[1][0], 0, 0, 0);
      acc2[1][1] = __builtin_amdgcn_mfma_f32_16x16x32_f16(A1, B1, acc2[1][1], 0, 0, 0);
    }
  }
  f32x4 w3a = *reinterpret_cast<const f32x4*>(&w3g[(2 * p + 0) * 16 + qd * 4]);
  f32x4 w3b = *reinterpret_cast<const f32x4*>(&w3g[(2 * p + 1) * 16 + qd * 4]);
#pragma unroll
  for (int dn = 0; dn < 2; ++dn) {
    float s = 0.f;
#pragma unroll
    for (int r = 0; r < 4; ++r) s += w3a[r] * gelu_fast(acc2[0][dn][r] * 16.f);
#pragma unroll
    for (int r = 0; r < 4; ++r) s += w3b[r] * gelu_fast(acc2[1][dn][r] * 16.f);
    s += __shfl_xor(s, 16);
    s += __shfl_xor(s, 32);
    if (lane < 16) sPart[p][(2 * nq + dn) * 16 + lane] = s;
  }
  __syncthreads();
  if (tid < 128) {
    int t = t0 + tid;
    float logit = sPart[0][tid] + sPart[1][tid] + b3g[0];
    float m = amask[(size_t)b * T_ + t];
    lp[(size_t)b * T_ + t] = (1.f / (1.f + expf(-logit))) * m;
  }
}

// ---------------- Kernel D: smooth learned + blend (unchanged) ----------------
__global__ __launch_bounds__(256)
void final_k(const float* __restrict__ rule, const float* __restrict__ lp,
             const float* __restrict__ amask, float* __restrict__ out) {
  int idx = blockIdx.x * 256 + threadIdx.x;
  if (idx >= BT) return;
  int t = idx & (T_ - 1);
  float s = 0.f;
#pragma unroll
  for (int d = -2; d <= 2; ++d) {
    int tt = t + d;
    if (tt >= 0 && tt < T_) s += lp[idx + d];
  }
  float m = amask[idx];
  float learned = clip01(s * 0.2f * m);
  out[idx] = clip01(0.5f * rule[idx] + 0.5f * learned) * m;
}

}  // namespace

extern "C" void kernel_launch(void* const* d_in, const int* in_sizes, int n_in,
                              void* d_out, int out_size, void* d_ws, size_t ws_size,
                              hipStream_t stream) {
  const float* traj      = (const float*)d_in[0];
  const float* intervals = (const float*)d_in[1];
  const float* amask     = (const float*)d_in[2];
  const float* omask     = (const float*)d_in[3];
  const float* w1        = (const float*)d_in[4];
  const float* b1        = (const float*)d_in[5];
  const float* w2        = (const float*)d_in[6];
  const float* b2        = (const float*)d_in[7];
  const float* w3        = (const float*)d_in[8];
  const float* b3        = (const float*)d_in[9];
  float* out = (float*)d_out;
  float* ws = (float*)d_ws;

  float* feats = ws + OFF_FEATS;
  float* hc   = ws + OFF_HC;
  float* an   = ws + OFF_AN;
  float* sc   = ws + OFF_SC;
  float* ot   = ws + OFF_OT;
  float* rule = ws + OFF_RULE;
  float* lp   = ws + OFF_LP;
  float* scales = ws + OFF_SCALES;
  half8* w1f = (half8*)(ws + OFF_W1F);
  half8* w2f = (half8*)(ws + OFF_W2F);

  featurize_k<<<BT / 256, 256, 0, stream>>>(traj, intervals, amask, omask,
                                            feats, hc, an, sc, ot);
  scale_k<<<dim3(B_, 3), 256, 0, stream>>>(hc, an, sc, amask, scales);
  rule2_k<<<B_, 256, 0, stream>>>(hc, an, sc, ot, amask, scales, rule);
  repack_k<<<12, 256, 0, stream>>>(w1, w2, w1f, w2f);
  conv_k<<<dim3(T_ / TTILE, B_), 512, 0, stream>>>(feats, w1f, b1, w2f, b2, w3, b3, amask, lp);
  final_k<<<BT / 256, 256, 0, stream>>>(rule, lp, amask, out);
}